// Round 10
// baseline (291.904 us; speedup 1.0000x reference)
//
#include <hip/hip_runtime.h>
#include <hip/hip_bf16.h>

// Round 16: weff fused into ctx (ctx_weff_fused). The (b,h) ctx block
// already holds the full 64x64 context tile in LDS; apply 1/rowsum there
// and run weff's verified 4x4 micro-kernel over the 8 c-chunks in-block,
// writing WeffT directly. Removes the weff dispatch + the 4MB fp32 ctx
// round-trip. ctx block upgraded to 512 threads: 8-wave k-split for the
// K/V HBM stream, parallel 2-round acc reduction (was 4-phase serial).
// Same fp32 math as the split path (identical rounding).
// Everything else identical to round 15.
//
// Pipeline:
//   Xt[b][n][c]    = x transposed+converted        @0      (32 MB)
//   WT = [WqT | WkT | WvT] [hd][c]                 @121634816 (1.5 MB)
//   Wqb = straight bf16 Wq [ci][hd]                @123207680 (0.5 MB)
//   KV[b][hd2][n]  = gemm256(A=[WkT;WvT], B=Xt)    @33554432 (64 MB)
//                    rows 0-511 = K (RAW), 512-1023 = V
//   WeffT[b][c][hd]= softmax(K).V^T . Wp fused     @104857600 (16 MB)
//   Ft[b][c][ci]   = gemm128(A=WeffT, B=Wqb)       @33554432 (16 MB)
//   out[b][c][n]   = gemm256(A=Ft, B=Xt) + bp      -> d_out

__device__ __forceinline__ float bf2f(unsigned short u) {
    union { unsigned int i; float f; } x;
    x.i = ((unsigned int)u) << 16;
    return x.f;
}
__device__ __forceinline__ unsigned short f2bf(float f) {
    unsigned int u = __float_as_uint(f);
    unsigned int lsb = (u >> 16) & 1u;
    u += 0x7fffu + lsb;             // RNE
    return (unsigned short)(u >> 16);
}

// async global->LDS, 16B per lane. LDS dest is the wave-uniform base;
// HW writes lane l's 16B at base + l*16.
__device__ __forceinline__ void glds16(const unsigned short* g, unsigned short* l) {
    __builtin_amdgcn_global_load_lds(
        (const __attribute__((address_space(1))) unsigned int*)g,
        (__attribute__((address_space(3))) unsigned int*)l,
        16, 0, 0);
}

typedef __bf16 bf16x8 __attribute__((ext_vector_type(8)));
typedef float  f32x4  __attribute__((ext_vector_type(4)));

// x [b][512 c][1024 n] (flag dtype) -> Xt [b][n][c] bf16 (row stride 512!)
// Also self-detects dtype (bf16 vs fp32) and publishes to *flag.
__global__ __launch_bounds__(256) void transpose_x(
    const void* __restrict__ in, unsigned short* __restrict__ out,
    int* __restrict__ flag)
{
    const int t = threadIdx.x;
    const unsigned short* xs = (const unsigned short*)in;
    unsigned short u0 = xs[2 * (t & 63)];
    int e0 = (u0 >> 7) & 0xFF;
    unsigned long long bm = __ballot(e0 >= 113 && e0 <= 142);
    const int fl = (__popcll(bm) >= 32) ? 1 : 0;
    if (blockIdx.x == 0 && blockIdx.y == 0 && blockIdx.z == 0 && t == 0)
        *flag = fl;

    const int b  = blockIdx.z;
    const int c0 = blockIdx.x * 64;   // over n (1024)
    const int r0 = blockIdx.y * 64;   // over c (512)
    __shared__ unsigned short Ts[64][68];
    const int tr  = t >> 4;
    const int tc4 = (t & 15) * 4;
    #pragma unroll
    for (int rr = 0; rr < 4; ++rr) {
        int rl = rr * 16 + tr;
        long off = (long)b * 524288 + (long)(r0 + rl) * 1024 + c0 + tc4;
        unsigned short v[4];
        if (fl) {
            ushort4 u = *(const ushort4*)((const unsigned short*)in + off);
            v[0] = u.x; v[1] = u.y; v[2] = u.z; v[3] = u.w;
        } else {
            float4 u = *(const float4*)((const float*)in + off);
            v[0] = f2bf(u.x); v[1] = f2bf(u.y); v[2] = f2bf(u.z); v[3] = f2bf(u.w);
        }
        #pragma unroll
        for (int q = 0; q < 4; ++q) Ts[tc4 + q][rl] = v[q];
    }
    __syncthreads();
    #pragma unroll
    for (int rr = 0; rr < 4; ++rr) {
        int cl = rr * 16 + tr;
        ushort4 o = *(const ushort4*)&Ts[cl][tc4];
        *(ushort4*)(out + (long)b * 524288 + (long)(c0 + cl) * 512 + r0 + tc4) = o;
    }
}

// W [512 c][512 hd] -> WT + z*262144 [512 hd][512 c], z picks Wq/Wk/Wv.
// z==0 additionally writes a straight bf16 copy of Wq to wqb [ci][hd].
__global__ __launch_bounds__(256) void transpose_w3(
    const void* __restrict__ w0, const void* __restrict__ w1,
    const void* __restrict__ w2, unsigned short* __restrict__ out,
    unsigned short* __restrict__ wqb,
    const int* __restrict__ flag)
{
    const int fl = *flag;
    const int z  = blockIdx.z;
    const void* in = (z == 0) ? w0 : (z == 1) ? w1 : w2;
    unsigned short* op = out + (long)z * 262144;
    const int c0 = blockIdx.x * 64;
    const int r0 = blockIdx.y * 64;
    __shared__ unsigned short Ts[64][68];
    const int t   = threadIdx.x;
    const int tr  = t >> 4;
    const int tc4 = (t & 15) * 4;
    #pragma unroll
    for (int rr = 0; rr < 4; ++rr) {
        int rl = rr * 16 + tr;
        long off = (long)(r0 + rl) * 512 + c0 + tc4;
        unsigned short v[4];
        if (fl) {
            ushort4 u = *(const ushort4*)((const unsigned short*)in + off);
            v[0] = u.x; v[1] = u.y; v[2] = u.z; v[3] = u.w;
        } else {
            float4 u = *(const float4*)((const float*)in + off);
            v[0] = f2bf(u.x); v[1] = f2bf(u.y); v[2] = f2bf(u.z); v[3] = f2bf(u.w);
        }
        if (z == 0) {   // straight bf16 Wq copy for the F-fold gemm B-operand
            ushort4 s; s.x = v[0]; s.y = v[1]; s.z = v[2]; s.w = v[3];
            *(ushort4*)(wqb + off) = s;
        }
        #pragma unroll
        for (int q = 0; q < 4; ++q) Ts[tc4 + q][rl] = v[q];
    }
    __syncthreads();
    #pragma unroll
    for (int rr = 0; rr < 4; ++rr) {
        int cl = rr * 16 + tr;
        ushort4 o = *(const ushort4*)&Ts[cl][tc4];
        *(ushort4*)(op + (long)(c0 + cl) * 512 + r0 + tc4) = o;
    }
}

// ===================== 256x256 GEMM, 16 waves =====================
// C = A . B^T : A [M][K] bf16 k-contig, B [N][K] bf16 k-contig, fp32 acc.
// 1024 threads = 16 waves (4M x 4N), per-wave C = 64x64. BK=64, 2 K-tile
// LDS dbuf (128KB). Counted vmcnt(4). Slot swizzle: conflict-free (r12).
// XCD-aware bijective tile remap (T1, verified: FETCH 37->24.6 MB).
// M,N multiples of 256; K multiple of 64; gridDim product % 8 == 0.
// mode 0: C bf16 [M][N]; mode 2: +bias[m], dtype per flag.
__global__ __launch_bounds__(1024, 4) void gemm_bt_256(
    const unsigned short* __restrict__ A, long a_bstride,
    const unsigned short* __restrict__ Bm, long b_bstride,
    void* __restrict__ C, long c_bstride,
    const void* __restrict__ bias,
    int M, int N, int K, int mode,
    const int* __restrict__ flag)
{
    // ---- T1 tile remap
    const int gx = gridDim.x, gy = gridDim.y;
    const int nwg = gx * gy * (int)gridDim.z;
    const int lid = blockIdx.x + gx * (blockIdx.y + gy * blockIdx.z);
    const int swzid = (lid & 7) * (nwg >> 3) + (lid >> 3);
    const int bx = swzid % gx;
    const int by = (swzid / gx) % gy;
    const int bz = swzid / (gx * gy);

    const int b  = bz;
    const int n0 = bx * 256;
    const int m0 = by * 256;
    const unsigned short* Ab = A  + (long)b * a_bstride;
    const unsigned short* Bb = Bm + (long)b * b_bstride;

    __shared__ unsigned short S[65536];

    const int t  = threadIdx.x;       // 0..1023
    const int w  = t >> 6;            // 0..15
    const int l  = t & 63;
    const int fm = l & 15;
    const int kg = l >> 4;
    const int wr = w >> 2;            // 0..3  (M quarter)
    const int wc = w & 3;             // 0..3  (N quarter)

    const int rowb = w * 8 + (l >> 3);
    const int swz  = ((l & 7) ^ (l >> 3)) * 8;   // element offset
    const unsigned short* gA = Ab + (long)(m0 + rowb) * K + swz;
    const unsigned short* gB = Bb + (long)(n0 + rowb) * K + swz;

    const int sA = fm & 7;

    f32x4 acc[4][4] = {};

    const int NT = K >> 6;            // K-tiles of 64

    auto STAGE = [&](int kt, int buf) {
        const long ko = (long)kt * 64;
        unsigned short* Ld = &S[buf * 32768];
        #pragma unroll
        for (int r = 0; r < 2; ++r)
            glds16(gA + (long)r * 128 * K + ko, Ld + (r * 128 + w * 8) * 64);
        #pragma unroll
        for (int r = 0; r < 2; ++r)
            glds16(gB + (long)r * 128 * K + ko, Ld + 16384 + (r * 128 + w * 8) * 64);
    };

    STAGE(0, 0);

    for (int tt = 0; tt < NT; ++tt) {
        if (tt + 1 < NT) {
            STAGE(tt + 1, (tt + 1) & 1);
            __builtin_amdgcn_sched_barrier(0);
            asm volatile("s_waitcnt vmcnt(4)" ::: "memory");   // tile tt landed
        } else {
            __builtin_amdgcn_sched_barrier(0);
            asm volatile("s_waitcnt vmcnt(0)" ::: "memory");
        }
        __builtin_amdgcn_sched_barrier(0);
        __builtin_amdgcn_s_barrier();        // all waves: buf[tt&1] published
        __builtin_amdgcn_sched_barrier(0);

        {
            const unsigned short* Abuf = &S[(tt & 1) * 32768];
            const unsigned short* Bbuf = Abuf + 16384;
            bf16x8 bf[4][2];
            #pragma unroll
            for (int j = 0; j < 4; ++j)
                #pragma unroll
                for (int kk = 0; kk < 2; ++kk) {
                    const int row = wc * 64 + j * 16 + fm;
                    bf[j][kk] = *(const bf16x8*)&Bbuf[row * 64 + ((kk * 4 + kg) ^ sA) * 8];
                }
            #pragma unroll
            for (int i = 0; i < 4; ++i) {
                bf16x8 af[2];
                #pragma unroll
                for (int kk = 0; kk < 2; ++kk) {
                    const int row = wr * 64 + i * 16 + fm;
                    af[kk] = *(const bf16x8*)&Abuf[row * 64 + ((kk * 4 + kg) ^ sA) * 8];
                }
                __builtin_amdgcn_s_setprio(1);
                #pragma unroll
                for (int j = 0; j < 4; ++j)
                    #pragma unroll
                    for (int kk = 0; kk < 2; ++kk)
                        acc[i][j] = __builtin_amdgcn_mfma_f32_16x16x32_bf16(
                            bf[j][kk], af[kk], acc[i][j], 0, 0, 0);
                __builtin_amdgcn_s_setprio(0);
            }
        }

        __builtin_amdgcn_sched_barrier(0);
        __builtin_amdgcn_s_barrier();        // buf[tt&1] free for tile tt+2
        __builtin_amdgcn_sched_barrier(0);
    }

    // epilogue (operand-swapped D): m per-lane fixed, 4 consecutive n/lane.
    const int fl = *flag;
    const long cb = (long)b * c_bstride;
    #pragma unroll
    for (int i = 0; i < 4; ++i) {
        const int m = m0 + wr * 64 + i * 16 + fm;
        float bv = 0.f;
        if (mode == 2 && bias)
            bv = fl ? bf2f(((const unsigned short*)bias)[m])
                    : ((const float*)bias)[m];
        #pragma unroll
        for (int j = 0; j < 4; ++j) {
            const int nb = n0 + wc * 64 + j * 16 + kg * 4;
            const long off = cb + (long)m * N + nb;
            if (mode == 0) {
                ushort4 o;
                o.x = f2bf(acc[i][j][0]); o.y = f2bf(acc[i][j][1]);
                o.z = f2bf(acc[i][j][2]); o.w = f2bf(acc[i][j][3]);
                *(ushort4*)&((unsigned short*)C)[off] = o;
            } else if (fl) {
                ushort4 o;
                o.x = f2bf(acc[i][j][0] + bv); o.y = f2bf(acc[i][j][1] + bv);
                o.z = f2bf(acc[i][j][2] + bv); o.w = f2bf(acc[i][j][3] + bv);
                *(ushort4*)&((unsigned short*)C)[off] = o;
            } else {
                float4 o;
                o.x = acc[i][j][0] + bv; o.y = acc[i][j][1] + bv;
                o.z = acc[i][j][2] + bv; o.w = acc[i][j][3] + bv;
                *(float4*)&((float*)C)[off] = o;
            }
        }
    }
}

// ===================== 128x128 GEMM (kept for Ft) =====================
__global__ __launch_bounds__(256) void gemm_bt_mfma(
    const unsigned short* __restrict__ A, long a_bstride,
    const unsigned short* __restrict__ Bm, long b_bstride,
    void* __restrict__ C, long c_bstride,
    const void* __restrict__ bias,
    int M, int N, int K, int mode,
    const int* __restrict__ flag)
{
    const int b  = blockIdx.z;
    const int n0 = blockIdx.x * 128;
    const int m0 = blockIdx.y * 128;
    const unsigned short* Ab = A  + (long)b * a_bstride;
    const unsigned short* Bb = Bm + (long)b * b_bstride;

    __shared__ unsigned short As[2 * 128 * 32];
    __shared__ unsigned short Bs[2 * 128 * 32];

    const int t    = threadIdx.x;
    const int w    = t >> 6;
    const int lane = t & 63;
    const int wm   = (w & 1) * 64;
    const int wn   = (w >> 1) * 64;
    const int fm   = lane & 15;
    const int kg   = lane >> 4;

    const int crow = lane >> 2;        // 0..15
    const int ccol = (lane & 3) * 8;   // element col within BK

    f32x4 acc[4][4] = {};

    #pragma unroll
    for (int j = 0; j < 2; ++j) {
        const int chunk = w * 2 + j;
        const int row   = chunk * 16 + crow;
        glds16(Ab + (long)(m0 + row) * K + ccol, &As[chunk * 512]);
        glds16(Bb + (long)(n0 + row) * K + ccol, &Bs[chunk * 512]);
    }

    int cur = 0;
    for (int k0 = 0; k0 < K; k0 += 32) {
        __syncthreads();

        if (k0 + 32 < K) {
            const int kn  = k0 + 32;
            const int nxt = (cur ^ 1) * 4096;
            #pragma unroll
            for (int j = 0; j < 2; ++j) {
                const int chunk = w * 2 + j;
                const int row   = chunk * 16 + crow;
                glds16(Ab + (long)(m0 + row) * K + kn + ccol, &As[nxt + chunk * 512]);
                glds16(Bb + (long)(n0 + row) * K + kn + ccol, &Bs[nxt + chunk * 512]);
            }
        }

        const int bufo = cur * 4096;
        bf16x8 af[4], bf[4];
        #pragma unroll
        for (int i = 0; i < 4; ++i)
            af[i] = *(const bf16x8*)&As[bufo + (wm + i * 16 + fm) * 32 + kg * 8];
        #pragma unroll
        for (int j = 0; j < 4; ++j)
            bf[j] = *(const bf16x8*)&Bs[bufo + (wn + j * 16 + fm) * 32 + kg * 8];
        #pragma unroll
        for (int i = 0; i < 4; ++i)
            #pragma unroll
            for (int j = 0; j < 4; ++j)
                acc[i][j] = __builtin_amdgcn_mfma_f32_16x16x32_bf16(
                    bf[j], af[i], acc[i][j], 0, 0, 0);
        cur ^= 1;
    }

    const int fl = *flag;
    const long cb = (long)b * c_bstride;
    #pragma unroll
    for (int i = 0; i < 4; ++i) {
        const int m = m0 + wm + i * 16 + fm;
        float bv = 0.f;
        if (mode == 2 && bias)
            bv = fl ? bf2f(((const unsigned short*)bias)[m])
                    : ((const float*)bias)[m];
        #pragma unroll
        for (int j = 0; j < 4; ++j) {
            const int nb = n0 + wn + j * 16 + kg * 4;
            const long off = cb + (long)m * N + nb;
            if (mode == 0) {
                ushort4 o;
                o.x = f2bf(acc[i][j][0]); o.y = f2bf(acc[i][j][1]);
                o.z = f2bf(acc[i][j][2]); o.w = f2bf(acc[i][j][3]);
                *(ushort4*)&((unsigned short*)C)[off] = o;
            } else if (fl) {
                ushort4 o;
                o.x = f2bf(acc[i][j][0] + bv); o.y = f2bf(acc[i][j][1] + bv);
                o.z = f2bf(acc[i][j][2] + bv); o.w = f2bf(acc[i][j][3] + bv);
                *(ushort4*)&((unsigned short*)C)[off] = o;
            } else {
                float4 o;
                o.x = acc[i][j][0] + bv; o.y = acc[i][j][1] + bv;
                o.z = acc[i][j][2] + bv; o.w = acc[i][j][3] + bv;
                *(float4*)&((float*)C)[off] = o;
            }
        }
    }
}

// Fused: WeffT[b][c][h*64+d] = sum_v ( softmax_n(K) . V^T )[d][v] * Wp[h*64+v][c]
// Phase A (512 thr, 8-wave k-split): single-pass exp + MFMA, row sums
// from the same exp values (partition n = w*128 + c*32 + kg*8 + z).
// Phase B: parallel acc reduction into red[64][65], scaled by 1/rowsum.
// Phase C: weff micro-kernel (verbatim indexing from the split kernel),
// 2 c-chunks concurrently (half = t>>8), 4 chunk-iterations.
__global__ __launch_bounds__(512) void ctx_weff_fused(
    const unsigned short* __restrict__ KV,
    const void* __restrict__ Wp,            // [512,512] flag dtype, c-contig
    unsigned short* __restrict__ WeffT,     // [B,512,512] bf16, hd-contig
    const int* __restrict__ flag)
{
    const int bh = blockIdx.x;
    const int b  = bh >> 3;
    const int h  = bh & 7;
    const unsigned short* Kb = KV + ((long)b << 20) + (long)h * 65536;
    const unsigned short* Vb = Kb + 524288;   // V half of KV

    const int t    = threadIdx.x;   // 0..511
    const int w    = t >> 6;        // 0..7
    const int lane = t & 63;
    const int fm   = lane & 15;
    const int kg   = lane >> 4;

    __shared__ float red4[4][64][65];   // 66.6 KB
    __shared__ float Ws[2][64][68];     // 34.8 KB
    __shared__ float sred[8][64];
    __shared__ float sinv[64];

    f32x4 acc[4][4] = {};
    float sloc[4] = {0.f, 0.f, 0.f, 0.f};

    // ---- Phase A: each wave covers n in [w*128, w*128+128)
    #pragma unroll
    for (int c = 0; c < 4; ++c) {
        const int k0 = w * 128 + c * 32;
        bf16x8 af[4], bf[4];
        #pragma unroll
        for (int i = 0; i < 4; ++i) {
            uint4 u = *(const uint4*)(Kb + (long)(i * 16 + fm) * 1024 + k0 + kg * 8);
            unsigned short o[8];
            #pragma unroll
            for (int z = 0; z < 4; ++z) {
                unsigned int uu = ((const unsigned int*)&u)[z];
                float lo = __expf(bf2f((unsigned short)(uu & 0xffffu)));
                float hi = __expf(bf2f((unsigned short)(uu >> 16)));
                sloc[i] += lo + hi;
                o[2 * z]     = f2bf(lo);
                o[2 * z + 1] = f2bf(hi);
            }
            af[i] = *(const bf16x8*)o;
        }
        #pragma unroll
        for (int j = 0; j < 4; ++j)
            bf[j] = *(const bf16x8*)(Vb + (long)(j * 16 + fm) * 1024 + k0 + kg * 8);
        #pragma unroll
        for (int i = 0; i < 4; ++i)
            #pragma unroll
            for (int j = 0; j < 4; ++j)
                acc[i][j] = __builtin_amdgcn_mfma_f32_16x16x32_bf16(
                    af[i], bf[j], acc[i][j], 0, 0, 0);
    }

    // fold kg (lane bits 4,5) -> per-wave row partial sums
    #pragma unroll
    for (int i = 0; i < 4; ++i) {
        sloc[i] += __shfl_xor(sloc[i], 16, 64);
        sloc[i] += __shfl_xor(sloc[i], 32, 64);
    }
    if (kg == 0) {
        #pragma unroll
        for (int i = 0; i < 4; ++i) sred[w][i * 16 + fm] = sloc[i];
    }

    // ---- Phase B: parallel reduction of the 8 wave-accs
    if (w < 4) {
        #pragma unroll
        for (int i = 0; i < 4; ++i)
            #pragma unroll
            for (int j = 0; j < 4; ++j)
                #pragma unroll
                for (int r = 0; r < 4; ++r)
                    red4[w][i * 16 + kg * 4 + r][j * 16 + fm] = acc[i][j][r];
    }
    __syncthreads();
    if (w >= 4) {
        #pragma unroll
        for (int i = 0; i < 4; ++i)
            #pragma unroll
            for (int j = 0; j < 4; ++j)
                #pragma unroll
                for (int r = 0; r < 4; ++r)
                    red4[w - 4][i * 16 + kg * 4 + r][j * 16 + fm] += acc[i][j][r];
    }
    if (t < 64) {
        float s = 0.f;
        #pragma unroll
        for (int q = 0; q < 8; ++q) s += sred[q][t];
        sinv[t] = 1.0f / s;
    }
    __syncthreads();
    for (int i = t; i < 4096; i += 512) {
        const int m = i >> 6, n = i & 63;
        red4[0][m][n] = (red4[0][m][n] + red4[1][m][n] +
                         red4[2][m][n] + red4[3][m][n]) * sinv[m];
    }
    __syncthreads();

    // ---- Phase C: weff micro-kernel over c-chunks (2 concurrent halves)
    const int fl   = *flag;
    const int half = t >> 8;        // 0,1
    const int th   = t & 255;
    const int tx   = th & 15, ty = th >> 4;

    for (int chunk = 0; chunk < 4; ++chunk) {
        const int c0 = chunk * 128 + half * 64;
        for (int i = th; i < 4096; i += 256) {
            const int v = i >> 6, c = i & 63;
            const long idx = (long)(h * 64 + v) * 512 + c0 + c;
            Ws[half][v][c] = fl ? bf2f(((const unsigned short*)Wp)[idx])
                                : ((const float*)Wp)[idx];
        }
        __syncthreads();

        float wacc[4][4];
        #pragma unroll
        for (int i = 0; i < 4; ++i)
            #pragma unroll
            for (int j = 0; j < 4; ++j) wacc[i][j] = 0.f;

        #pragma unroll 8
        for (int v = 0; v < 64; ++v) {
            float a[4], d[4];
            #pragma unroll
            for (int i = 0; i < 4; ++i) a[i] = Ws[half][v][ty * 4 + i];  // over c
            #pragma unroll
            for (int j = 0; j < 4; ++j) d[j] = red4[0][tx * 4 + j][v];   // over d
            #pragma unroll
            for (int i = 0; i < 4; ++i)
                #pragma unroll
                for (int j = 0; j < 4; ++j) wacc[i][j] += a[i] * d[j];
        }
        #pragma unroll
        for (int i = 0; i < 4; ++i) {
            ushort4 o;
            o.x = f2bf(wacc[i][0]); o.y = f2bf(wacc[i][1]);
            o.z = f2bf(wacc[i][2]); o.w = f2bf(wacc[i][3]);
            *(ushort4*)&WeffT[((long)b * 512 + c0 + ty * 4 + i) * 512 + h * 64 + tx * 4] = o;
        }
        __syncthreads();   // Ws reload safe
    }
}

extern "C" void kernel_launch(void* const* d_in, const int* in_sizes, int n_in,
                              void* d_out, int out_size, void* d_ws, size_t ws_size,
                              hipStream_t stream) {
    const void* x  = d_in[0];
    const void* Wq = d_in[1];
    const void* Wk = d_in[2];
    const void* Wv = d_in[3];
    const void* Wp = d_in[4];
    const void* bp = d_in[5];

    char* ws = (char*)d_ws;
    unsigned short* Xt    = (unsigned short*)(ws);                // 32 MB [b][n][c]
    unsigned short* KV    = (unsigned short*)(ws + 33554432ll);   // 64 MB [b][1024][1024]
    unsigned short* Ft    = (unsigned short*)(ws + 33554432ll);   // 16 MB (reuse after ctx)
    unsigned short* WeffT = (unsigned short*)(ws + 104857600ll);  // 16 MB
    unsigned short* WT    = (unsigned short*)(ws + 121634816ll);  // 1.5 MB [WqT|WkT|WvT]
    unsigned short* Wqb   = (unsigned short*)(ws + 123207680ll);  // 0.5 MB straight Wq bf16
    int*            flag  = (int*)(ws + 123731968ll);

    // transpose_x self-detects dtype and publishes *flag.
    transpose_x<<<dim3(16, 8, 32), 256, 0, stream>>>(x, Xt, flag);
    transpose_w3<<<dim3(8, 8, 3), 256, 0, stream>>>(Wq, Wk, Wv, WT, Wqb, flag);

    const long XB = 1024ll * 512;
    // KV[b][hd2][n] = [WkT;WvT] . Xt^T   (M=1024, N=1024, K=512)
    gemm_bt_256<<<dim3(4, 4, 32), 1024, 0, stream>>>(
        WT + 262144, 0, Xt, XB, KV, 1048576ll, nullptr, 1024, 1024, 512, 0, flag);

    // fused single-pass softmax + ctx + weff -> WeffT
    ctx_weff_fused<<<dim3(256), 512, 0, stream>>>(KV, Wp, WeffT, flag);

    // Ft[b][c][ci] = WeffT . Wq^T   (M=512, N=512, K=512); KV dead -> reuse
    gemm_bt_mfma<<<dim3(4, 4, 32), 256, 0, stream>>>(
        WeffT, 262144ll, Wqb, 0, Ft, 262144ll, nullptr, 512, 512, 512, 0, flag);

    // out[b][c][n] = Ft . Xt^T + bp   (M=512, N=1024, K=512)
    gemm_bt_256<<<dim3(4, 2, 32), 1024, 0, stream>>>(
        Ft, 262144ll, Xt, XB, d_out, 524288ll, bp, 512, 1024, 512, 2, flag);
}

// Round 11
// 283.147 us; speedup vs baseline: 1.0309x; 1.0309x over previous
//
#include <hip/hip_runtime.h>
#include <hip/hip_bf16.h>

// Round 17: REVERT to round 15 (284.1 us, session best). Round 16's
// ctx+weff fusion regressed (68.6us fused vs ~28us split): 104KB LDS ->
// 1 block/CU -> 2 waves/SIMD, three serial in-block phases that the
// split path overlapped across CUs via the dispatch pipeline, + 3.5M
// new bank conflicts in the phase-B scatter. Consolidation exhausted.
//
// Pipeline:
//   Xt[b][n][c]    = x transposed+converted        @0      (32 MB)
//   WT = [WqT | WkT | WvT] [hd][c]                 @121634816 (1.5 MB)
//   Wqb = straight bf16 Wq [ci][hd]                @123207680 (0.5 MB)
//   KV[b][hd2][n]  = gemm256(A=[WkT;WvT], B=Xt)    @33554432 (64 MB)
//                    rows 0-511 = K (RAW), 512-1023 = V
//   ctx[b,h,d,v]   = softmax(K).V^T per (b,h)      @100663296 (4 MB fp32)
//   WeffT[b][c][hd]= sum_v ctx*Wp                  @104857600 (16 MB)
//   Ft[b][c][ci]   = gemm128(A=WeffT, B=Wqb)       @33554432 (16 MB)
//   out[b][c][n]   = gemm256(A=Ft, B=Xt) + bp      -> d_out

__device__ __forceinline__ float bf2f(unsigned short u) {
    union { unsigned int i; float f; } x;
    x.i = ((unsigned int)u) << 16;
    return x.f;
}
__device__ __forceinline__ unsigned short f2bf(float f) {
    unsigned int u = __float_as_uint(f);
    unsigned int lsb = (u >> 16) & 1u;
    u += 0x7fffu + lsb;             // RNE
    return (unsigned short)(u >> 16);
}

// async global->LDS, 16B per lane. LDS dest is the wave-uniform base;
// HW writes lane l's 16B at base + l*16.
__device__ __forceinline__ void glds16(const unsigned short* g, unsigned short* l) {
    __builtin_amdgcn_global_load_lds(
        (const __attribute__((address_space(1))) unsigned int*)g,
        (__attribute__((address_space(3))) unsigned int*)l,
        16, 0, 0);
}

typedef __bf16 bf16x8 __attribute__((ext_vector_type(8)));
typedef float  f32x4  __attribute__((ext_vector_type(4)));

// x [b][512 c][1024 n] (flag dtype) -> Xt [b][n][c] bf16 (row stride 512!)
// Also self-detects dtype (bf16 vs fp32) and publishes to *flag.
__global__ __launch_bounds__(256) void transpose_x(
    const void* __restrict__ in, unsigned short* __restrict__ out,
    int* __restrict__ flag)
{
    const int t = threadIdx.x;
    const unsigned short* xs = (const unsigned short*)in;
    unsigned short u0 = xs[2 * (t & 63)];
    int e0 = (u0 >> 7) & 0xFF;
    unsigned long long bm = __ballot(e0 >= 113 && e0 <= 142);
    const int fl = (__popcll(bm) >= 32) ? 1 : 0;
    if (blockIdx.x == 0 && blockIdx.y == 0 && blockIdx.z == 0 && t == 0)
        *flag = fl;

    const int b  = blockIdx.z;
    const int c0 = blockIdx.x * 64;   // over n (1024)
    const int r0 = blockIdx.y * 64;   // over c (512)
    __shared__ unsigned short Ts[64][68];
    const int tr  = t >> 4;
    const int tc4 = (t & 15) * 4;
    #pragma unroll
    for (int rr = 0; rr < 4; ++rr) {
        int rl = rr * 16 + tr;
        long off = (long)b * 524288 + (long)(r0 + rl) * 1024 + c0 + tc4;
        unsigned short v[4];
        if (fl) {
            ushort4 u = *(const ushort4*)((const unsigned short*)in + off);
            v[0] = u.x; v[1] = u.y; v[2] = u.z; v[3] = u.w;
        } else {
            float4 u = *(const float4*)((const float*)in + off);
            v[0] = f2bf(u.x); v[1] = f2bf(u.y); v[2] = f2bf(u.z); v[3] = f2bf(u.w);
        }
        #pragma unroll
        for (int q = 0; q < 4; ++q) Ts[tc4 + q][rl] = v[q];
    }
    __syncthreads();
    #pragma unroll
    for (int rr = 0; rr < 4; ++rr) {
        int cl = rr * 16 + tr;
        ushort4 o = *(const ushort4*)&Ts[cl][tc4];
        // Xt row (n = c0+cl) has 512 elements (c-dim) -> stride 512
        *(ushort4*)(out + (long)b * 524288 + (long)(c0 + cl) * 512 + r0 + tc4) = o;
    }
}

// W [512 c][512 hd] -> WT + z*262144 [512 hd][512 c], z picks Wq/Wk/Wv.
// z==0 additionally writes a straight bf16 copy of Wq to wqb [ci][hd].
__global__ __launch_bounds__(256) void transpose_w3(
    const void* __restrict__ w0, const void* __restrict__ w1,
    const void* __restrict__ w2, unsigned short* __restrict__ out,
    unsigned short* __restrict__ wqb,
    const int* __restrict__ flag)
{
    const int fl = *flag;
    const int z  = blockIdx.z;
    const void* in = (z == 0) ? w0 : (z == 1) ? w1 : w2;
    unsigned short* op = out + (long)z * 262144;
    const int c0 = blockIdx.x * 64;
    const int r0 = blockIdx.y * 64;
    __shared__ unsigned short Ts[64][68];
    const int t   = threadIdx.x;
    const int tr  = t >> 4;
    const int tc4 = (t & 15) * 4;
    #pragma unroll
    for (int rr = 0; rr < 4; ++rr) {
        int rl = rr * 16 + tr;
        long off = (long)(r0 + rl) * 512 + c0 + tc4;
        unsigned short v[4];
        if (fl) {
            ushort4 u = *(const ushort4*)((const unsigned short*)in + off);
            v[0] = u.x; v[1] = u.y; v[2] = u.z; v[3] = u.w;
        } else {
            float4 u = *(const float4*)((const float*)in + off);
            v[0] = f2bf(u.x); v[1] = f2bf(u.y); v[2] = f2bf(u.z); v[3] = f2bf(u.w);
        }
        if (z == 0) {   // straight bf16 Wq copy for the F-fold gemm B-operand
            ushort4 s; s.x = v[0]; s.y = v[1]; s.z = v[2]; s.w = v[3];
            *(ushort4*)(wqb + off) = s;
        }
        #pragma unroll
        for (int q = 0; q < 4; ++q) Ts[tc4 + q][rl] = v[q];
    }
    __syncthreads();
    #pragma unroll
    for (int rr = 0; rr < 4; ++rr) {
        int cl = rr * 16 + tr;
        ushort4 o = *(const ushort4*)&Ts[cl][tc4];
        *(ushort4*)(op + (long)(c0 + cl) * 512 + r0 + tc4) = o;
    }
}

// ===================== 256x256 GEMM, 16 waves =====================
// C = A . B^T : A [M][K] bf16 k-contig, B [N][K] bf16 k-contig, fp32 acc.
// 1024 threads = 16 waves (4M x 4N), per-wave C = 64x64. BK=64, 2 K-tile
// LDS dbuf (128KB). Counted vmcnt(4). Slot swizzle: conflict-free (r12).
// XCD-aware bijective tile remap (T1, verified: FETCH 37->24.6 MB).
// M,N multiples of 256; K multiple of 64; gridDim product % 8 == 0.
// mode 0: C bf16 [M][N]; mode 2: +bias[m], dtype per flag.
__global__ __launch_bounds__(1024, 4) void gemm_bt_256(
    const unsigned short* __restrict__ A, long a_bstride,
    const unsigned short* __restrict__ Bm, long b_bstride,
    void* __restrict__ C, long c_bstride,
    const void* __restrict__ bias,
    int M, int N, int K, int mode,
    const int* __restrict__ flag)
{
    // ---- T1 tile remap
    const int gx = gridDim.x, gy = gridDim.y;
    const int nwg = gx * gy * (int)gridDim.z;
    const int lid = blockIdx.x + gx * (blockIdx.y + gy * blockIdx.z);
    const int swzid = (lid & 7) * (nwg >> 3) + (lid >> 3);
    const int bx = swzid % gx;
    const int by = (swzid / gx) % gy;
    const int bz = swzid / (gx * gy);

    const int b  = bz;
    const int n0 = bx * 256;
    const int m0 = by * 256;
    const unsigned short* Ab = A  + (long)b * a_bstride;
    const unsigned short* Bb = Bm + (long)b * b_bstride;

    __shared__ unsigned short S[65536];

    const int t  = threadIdx.x;       // 0..1023
    const int w  = t >> 6;            // 0..15
    const int l  = t & 63;
    const int fm = l & 15;
    const int kg = l >> 4;
    const int wr = w >> 2;            // 0..3  (M quarter)
    const int wc = w & 3;             // 0..3  (N quarter)

    const int rowb = w * 8 + (l >> 3);
    const int swz  = ((l & 7) ^ (l >> 3)) * 8;   // element offset
    const unsigned short* gA = Ab + (long)(m0 + rowb) * K + swz;
    const unsigned short* gB = Bb + (long)(n0 + rowb) * K + swz;

    const int sA = fm & 7;

    f32x4 acc[4][4] = {};

    const int NT = K >> 6;            // K-tiles of 64

    auto STAGE = [&](int kt, int buf) {
        const long ko = (long)kt * 64;
        unsigned short* Ld = &S[buf * 32768];
        #pragma unroll
        for (int r = 0; r < 2; ++r)
            glds16(gA + (long)r * 128 * K + ko, Ld + (r * 128 + w * 8) * 64);
        #pragma unroll
        for (int r = 0; r < 2; ++r)
            glds16(gB + (long)r * 128 * K + ko, Ld + 16384 + (r * 128 + w * 8) * 64);
    };

    STAGE(0, 0);

    for (int tt = 0; tt < NT; ++tt) {
        if (tt + 1 < NT) {
            STAGE(tt + 1, (tt + 1) & 1);
            __builtin_amdgcn_sched_barrier(0);
            asm volatile("s_waitcnt vmcnt(4)" ::: "memory");   // tile tt landed
        } else {
            __builtin_amdgcn_sched_barrier(0);
            asm volatile("s_waitcnt vmcnt(0)" ::: "memory");
        }
        __builtin_amdgcn_sched_barrier(0);
        __builtin_amdgcn_s_barrier();        // all waves: buf[tt&1] published
        __builtin_amdgcn_sched_barrier(0);

        {
            const unsigned short* Abuf = &S[(tt & 1) * 32768];
            const unsigned short* Bbuf = Abuf + 16384;
            bf16x8 bf[4][2];
            #pragma unroll
            for (int j = 0; j < 4; ++j)
                #pragma unroll
                for (int kk = 0; kk < 2; ++kk) {
                    const int row = wc * 64 + j * 16 + fm;
                    bf[j][kk] = *(const bf16x8*)&Bbuf[row * 64 + ((kk * 4 + kg) ^ sA) * 8];
                }
            #pragma unroll
            for (int i = 0; i < 4; ++i) {
                bf16x8 af[2];
                #pragma unroll
                for (int kk = 0; kk < 2; ++kk) {
                    const int row = wr * 64 + i * 16 + fm;
                    af[kk] = *(const bf16x8*)&Abuf[row * 64 + ((kk * 4 + kg) ^ sA) * 8];
                }
                __builtin_amdgcn_s_setprio(1);
                #pragma unroll
                for (int j = 0; j < 4; ++j)
                    #pragma unroll
                    for (int kk = 0; kk < 2; ++kk)
                        acc[i][j] = __builtin_amdgcn_mfma_f32_16x16x32_bf16(
                            bf[j][kk], af[kk], acc[i][j], 0, 0, 0);
                __builtin_amdgcn_s_setprio(0);
            }
        }

        __builtin_amdgcn_sched_barrier(0);
        __builtin_amdgcn_s_barrier();        // buf[tt&1] free for tile tt+2
        __builtin_amdgcn_sched_barrier(0);
    }

    // epilogue (operand-swapped D): m per-lane fixed, 4 consecutive n/lane.
    const int fl = *flag;
    const long cb = (long)b * c_bstride;
    #pragma unroll
    for (int i = 0; i < 4; ++i) {
        const int m = m0 + wr * 64 + i * 16 + fm;
        float bv = 0.f;
        if (mode == 2 && bias)
            bv = fl ? bf2f(((const unsigned short*)bias)[m])
                    : ((const float*)bias)[m];
        #pragma unroll
        for (int j = 0; j < 4; ++j) {
            const int nb = n0 + wc * 64 + j * 16 + kg * 4;
            const long off = cb + (long)m * N + nb;
            if (mode == 0) {
                ushort4 o;
                o.x = f2bf(acc[i][j][0]); o.y = f2bf(acc[i][j][1]);
                o.z = f2bf(acc[i][j][2]); o.w = f2bf(acc[i][j][3]);
                *(ushort4*)&((unsigned short*)C)[off] = o;
            } else if (fl) {
                ushort4 o;
                o.x = f2bf(acc[i][j][0] + bv); o.y = f2bf(acc[i][j][1] + bv);
                o.z = f2bf(acc[i][j][2] + bv); o.w = f2bf(acc[i][j][3] + bv);
                *(ushort4*)&((unsigned short*)C)[off] = o;
            } else {
                float4 o;
                o.x = acc[i][j][0] + bv; o.y = acc[i][j][1] + bv;
                o.z = acc[i][j][2] + bv; o.w = acc[i][j][3] + bv;
                *(float4*)&((float*)C)[off] = o;
            }
        }
    }
}

// ===================== 128x128 GEMM (kept for Ft) =====================
__global__ __launch_bounds__(256) void gemm_bt_mfma(
    const unsigned short* __restrict__ A, long a_bstride,
    const unsigned short* __restrict__ Bm, long b_bstride,
    void* __restrict__ C, long c_bstride,
    const void* __restrict__ bias,
    int M, int N, int K, int mode,
    const int* __restrict__ flag)
{
    const int b  = blockIdx.z;
    const int n0 = blockIdx.x * 128;
    const int m0 = blockIdx.y * 128;
    const unsigned short* Ab = A  + (long)b * a_bstride;
    const unsigned short* Bb = Bm + (long)b * b_bstride;

    __shared__ unsigned short As[2 * 128 * 32];
    __shared__ unsigned short Bs[2 * 128 * 32];

    const int t    = threadIdx.x;
    const int w    = t >> 6;
    const int lane = t & 63;
    const int wm   = (w & 1) * 64;
    const int wn   = (w >> 1) * 64;
    const int fm   = lane & 15;
    const int kg   = lane >> 4;

    const int crow = lane >> 2;        // 0..15
    const int ccol = (lane & 3) * 8;   // element col within BK

    f32x4 acc[4][4] = {};

    #pragma unroll
    for (int j = 0; j < 2; ++j) {
        const int chunk = w * 2 + j;
        const int row   = chunk * 16 + crow;
        glds16(Ab + (long)(m0 + row) * K + ccol, &As[chunk * 512]);
        glds16(Bb + (long)(n0 + row) * K + ccol, &Bs[chunk * 512]);
    }

    int cur = 0;
    for (int k0 = 0; k0 < K; k0 += 32) {
        __syncthreads();

        if (k0 + 32 < K) {
            const int kn  = k0 + 32;
            const int nxt = (cur ^ 1) * 4096;
            #pragma unroll
            for (int j = 0; j < 2; ++j) {
                const int chunk = w * 2 + j;
                const int row   = chunk * 16 + crow;
                glds16(Ab + (long)(m0 + row) * K + kn + ccol, &As[nxt + chunk * 512]);
                glds16(Bb + (long)(n0 + row) * K + kn + ccol, &Bs[nxt + chunk * 512]);
            }
        }

        const int bufo = cur * 4096;
        bf16x8 af[4], bf[4];
        #pragma unroll
        for (int i = 0; i < 4; ++i)
            af[i] = *(const bf16x8*)&As[bufo + (wm + i * 16 + fm) * 32 + kg * 8];
        #pragma unroll
        for (int j = 0; j < 4; ++j)
            bf[j] = *(const bf16x8*)&Bs[bufo + (wn + j * 16 + fm) * 32 + kg * 8];
        #pragma unroll
        for (int i = 0; i < 4; ++i)
            #pragma unroll
            for (int j = 0; j < 4; ++j)
                acc[i][j] = __builtin_amdgcn_mfma_f32_16x16x32_bf16(
                    bf[j], af[i], acc[i][j], 0, 0, 0);
        cur ^= 1;
    }

    const int fl = *flag;
    const long cb = (long)b * c_bstride;
    #pragma unroll
    for (int i = 0; i < 4; ++i) {
        const int m = m0 + wm + i * 16 + fm;
        float bv = 0.f;
        if (mode == 2 && bias)
            bv = fl ? bf2f(((const unsigned short*)bias)[m])
                    : ((const float*)bias)[m];
        #pragma unroll
        for (int j = 0; j < 4; ++j) {
            const int nb = n0 + wn + j * 16 + kg * 4;
            const long off = cb + (long)m * N + nb;
            if (mode == 0) {
                ushort4 o;
                o.x = f2bf(acc[i][j][0]); o.y = f2bf(acc[i][j][1]);
                o.z = f2bf(acc[i][j][2]); o.w = f2bf(acc[i][j][3]);
                *(ushort4*)&((unsigned short*)C)[off] = o;
            } else if (fl) {
                ushort4 o;
                o.x = f2bf(acc[i][j][0] + bv); o.y = f2bf(acc[i][j][1] + bv);
                o.z = f2bf(acc[i][j][2] + bv); o.w = f2bf(acc[i][j][3] + bv);
                *(ushort4*)&((unsigned short*)C)[off] = o;
            } else {
                float4 o;
                o.x = acc[i][j][0] + bv; o.y = acc[i][j][1] + bv;
                o.z = acc[i][j][2] + bv; o.w = acc[i][j][3] + bv;
                *(float4*)&((float*)C)[off] = o;
            }
        }
    }
}

// ctx[b,h,d,v] = sum_n softmax_n(K)[b,h*64+d,n] * V[b,h*64+v,n].
// SINGLE PASS: softmax is shift-invariant and |K| is far below expf's
// fp32 range, so use raw p=exp(k) (no max pass). Row sums s[d] are
// accumulated from the same exp values that feed the MFMA A-fragments
// (lane partition n = w*256 + c*32 + kg*8 + z covers each n once);
// ctx = acc / s[d] at the write. K read ONCE from global.
__global__ __launch_bounds__(256) void ctx_softmax_mfma(
    const unsigned short* __restrict__ KV, float* __restrict__ ctx)
{
    const int bh = blockIdx.x;
    const unsigned short* Kb = KV + ((long)(bh >> 3) << 20) + (long)(bh & 7) * 65536;
    const unsigned short* Vb = Kb + 524288;   // V half of KV

    const int t    = threadIdx.x;
    const int w    = t >> 6;
    const int lane = t & 63;
    const int fm   = lane & 15;
    const int kg   = lane >> 4;

    f32x4 acc[4][4] = {};
    float sloc[4] = {0.f, 0.f, 0.f, 0.f};   // partial row-sums, rows i*16+fm

    #pragma unroll 2
    for (int c = 0; c < 8; ++c) {
        const int k0 = w * 256 + c * 32;
        bf16x8 af[4], bf[4];
        #pragma unroll
        for (int i = 0; i < 4; ++i) {
            uint4 u = *(const uint4*)(Kb + (long)(i * 16 + fm) * 1024 + k0 + kg * 8);
            unsigned short o[8];
            #pragma unroll
            for (int z = 0; z < 4; ++z) {
                unsigned int uu = ((const unsigned int*)&u)[z];
                float lo = __expf(bf2f((unsigned short)(uu & 0xffffu)));
                float hi = __expf(bf2f((unsigned short)(uu >> 16)));
                sloc[i] += lo + hi;
                o[2 * z]     = f2bf(lo);
                o[2 * z + 1] = f2bf(hi);
            }
            af[i] = *(const bf16x8*)o;
        }
        #pragma unroll
        for (int j = 0; j < 4; ++j)
            bf[j] = *(const bf16x8*)(Vb + (long)(j * 16 + fm) * 1024 + k0 + kg * 8);
        #pragma unroll
        for (int i = 0; i < 4; ++i)
            #pragma unroll
            for (int j = 0; j < 4; ++j)
                acc[i][j] = __builtin_amdgcn_mfma_f32_16x16x32_bf16(
                    af[i], bf[j], acc[i][j], 0, 0, 0);
    }

    // fold kg (lane bits 4,5): lanes with same fm then hold the wave sum
    __shared__ float sred[4][64];
    __shared__ float sinv[64];
    #pragma unroll
    for (int i = 0; i < 4; ++i) {
        sloc[i] += __shfl_xor(sloc[i], 16, 64);
        sloc[i] += __shfl_xor(sloc[i], 32, 64);
    }
    if (kg == 0) {
        #pragma unroll
        for (int i = 0; i < 4; ++i) sred[w][i * 16 + fm] = sloc[i];
    }
    __syncthreads();
    if (t < 64) sinv[t] = 1.0f / (sred[0][t] + sred[1][t] + sred[2][t] + sred[3][t]);

    __shared__ float red[64][65];
    for (int ph = 0; ph < 4; ++ph) {
        __syncthreads();
        if (w == ph) {
            #pragma unroll
            for (int i = 0; i < 4; ++i)
                #pragma unroll
                for (int j = 0; j < 4; ++j)
                    #pragma unroll
                    for (int r = 0; r < 4; ++r) {
                        const int m = i * 16 + kg * 4 + r;
                        const int n = j * 16 + fm;
                        if (ph == 0) red[m][n]  = acc[i][j][r];
                        else         red[m][n] += acc[i][j][r];
                    }
        }
    }
    __syncthreads();
    float* cp = ctx + (long)bh * 4096;
    for (int i = t; i < 4096; i += 256)
        cp[i] = red[i >> 6][i & 63] * sinv[i >> 6];
}

// WeffT[b][c][h*64+d] = sum_v ctx[b,h,d,v] * Wp[h*64+v][c]
__global__ __launch_bounds__(256) void weff_kernel(
    const float* __restrict__ ctx,          // [B,8,64,64] fp32
    const void* __restrict__ Wp,            // [512,512] flag dtype, c-contig
    unsigned short* __restrict__ WeffT,     // [B,512,512] bf16, hd-contig
    const int* __restrict__ flag)
{
    const int fl = *flag;
    const int c0 = blockIdx.x * 64;
    const int h  = blockIdx.y;
    const int b  = blockIdx.z;

    __shared__ float Cs[64][65];   // [d][v]
    __shared__ float Ws[64][68];   // [v][c]

    const int t = threadIdx.x;
    const int tx = t & 15, ty = t >> 4;

    const float* cb = ctx + ((long)b * 8 + h) * 4096;
    for (int i = t; i < 4096; i += 256) Cs[i >> 6][i & 63] = cb[i];
    for (int i = t; i < 4096; i += 256) {
        int v = i >> 6, c = i & 63;
        long idx = (long)(h * 64 + v) * 512 + c0 + c;
        Ws[v][c] = fl ? bf2f(((const unsigned short*)Wp)[idx])
                      : ((const float*)Wp)[idx];
    }
    __syncthreads();

    float acc[4][4];
    #pragma unroll
    for (int i = 0; i < 4; ++i)
        #pragma unroll
        for (int j = 0; j < 4; ++j) acc[i][j] = 0.f;

    #pragma unroll
    for (int v = 0; v < 64; ++v) {
        float a[4], d[4];
        #pragma unroll
        for (int i = 0; i < 4; ++i) a[i] = Ws[v][ty * 4 + i];   // over c
        #pragma unroll
        for (int j = 0; j < 4; ++j) d[j] = Cs[tx * 4 + j][v];   // over d
        #pragma unroll
        for (int i = 0; i < 4; ++i)
            #pragma unroll
            for (int j = 0; j < 4; ++j) acc[i][j] += a[i] * d[j];
    }
    #pragma unroll
    for (int i = 0; i < 4; ++i) {
        ushort4 o;
        o.x = f2bf(acc[i][0]); o.y = f2bf(acc[i][1]);
        o.z = f2bf(acc[i][2]); o.w = f2bf(acc[i][3]);
        *(ushort4*)&WeffT[((long)b * 512 + c0 + ty * 4 + i) * 512 + h * 64 + tx * 4] = o;
    }
}

extern "C" void kernel_launch(void* const* d_in, const int* in_sizes, int n_in,
                              void* d_out, int out_size, void* d_ws, size_t ws_size,
                              hipStream_t stream) {
    const void* x  = d_in[0];
    const void* Wq = d_in[1];
    const void* Wk = d_in[2];
    const void* Wv = d_in[3];
    const void* Wp = d_in[4];
    const void* bp = d_in[5];

    char* ws = (char*)d_ws;
    unsigned short* Xt    = (unsigned short*)(ws);                // 32 MB [b][n][c]
    unsigned short* KV    = (unsigned short*)(ws + 33554432ll);   // 64 MB [b][1024][1024]
    unsigned short* Ft    = (unsigned short*)(ws + 33554432ll);   // 16 MB (reuse after ctx)
    float*          ctx   = (float*)(ws + 100663296ll);           //  4 MB
    unsigned short* WeffT = (unsigned short*)(ws + 104857600ll);  // 16 MB
    unsigned short* WT    = (unsigned short*)(ws + 121634816ll);  // 1.5 MB [WqT|WkT|WvT]
    unsigned short* Wqb   = (unsigned short*)(ws + 123207680ll);  // 0.5 MB straight Wq bf16
    int*            flag  = (int*)(ws + 123731968ll);

    // transpose_x self-detects dtype and publishes *flag.
    transpose_x<<<dim3(16, 8, 32), 256, 0, stream>>>(x, Xt, flag);
    transpose_w3<<<dim3(8, 8, 3), 256, 0, stream>>>(Wq, Wk, Wv, WT, Wqb, flag);

    const long XB = 1024ll * 512;
    // KV[b][hd2][n] = [WkT;WvT] . Xt^T   (M=1024, N=1024, K=512)
    gemm_bt_256<<<dim3(4, 4, 32), 1024, 0, stream>>>(
        WT + 262144, 0, Xt, XB, KV, 1048576ll, nullptr, 1024, 1024, 512, 0, flag);

    // fused single-pass softmax + ctx
    ctx_softmax_mfma<<<dim3(256), 256, 0, stream>>>(KV, ctx);

    weff_kernel<<<dim3(8, 8, 32), 256, 0, stream>>>(ctx, Wp, WeffT, flag);

    // Ft[b][c][ci] = WeffT . Wq^T   (M=512, N=512, K=512); KV dead -> reuse
    gemm_bt_mfma<<<dim3(4, 4, 32), 256, 0, stream>>>(
        WeffT, 262144ll, Wqb, 0, Ft, 262144ll, nullptr, 512, 512, 512, 0, flag);

    // out[b][c][n] = Ft . Xt^T + bp   (M=512, N=1024, K=512)
    gemm_bt_256<<<dim3(4, 2, 32), 1024, 0, stream>>>(
        Ft, 262144ll, Xt, XB, d_out, 524288ll, bp, 512, 1024, 512, 2, flag);
}